// Round 1
// baseline (529.692 us; speedup 1.0000x reference)
//
#include <hip/hip_runtime.h>
#include <hip/hip_bf16.h>
#include <stdint.h>

#define NB 512
#define NL 128
#define ND 512

typedef __bf16 bf16;
typedef __bf16 bf16x8 __attribute__((ext_vector_type(8)));
typedef float  f32x4  __attribute__((ext_vector_type(4)));

// ---------------- K0: attT[n*512+k] = bf16(att[k*512+n]) ----------------
__global__ __launch_bounds__(256) void k_att_t(const float* __restrict__ att,
                                               bf16* __restrict__ attT) {
    int i = blockIdx.x * 256 + threadIdx.x;   // over 512*512
    int n = i >> 9, k = i & 511;
    attT[i] = (bf16)att[k * 512 + n];
}

// ---------------- K1: gather embed rows -> bf16, per-(b,side) sumsq ------
__global__ __launch_bounds__(256) void k_gather(const int* __restrict__ ctx1,
                                                const int* __restrict__ ctx2,
                                                const float* __restrict__ table,
                                                bf16* __restrict__ d1,
                                                bf16* __restrict__ d2,
                                                float* __restrict__ ss) {
    const int b = blockIdx.x, side = blockIdx.y, t = threadIdx.x;
    const int* __restrict__ ctx = side ? ctx2 : ctx1;
    bf16* __restrict__ dst = side ? d2 : d1;
    const int base = b * NL;
    float acc = 0.f;
    for (int i = t; i < NL * (ND / 4); i += 256) {
        int l = i >> 7, dv = i & 127;          // ND/4 = 128 float4 per row
        int idx = ctx[base + l];
        float4 v = ((const float4*)table)[(size_t)idx * (ND / 4) + dv];
        acc += v.x * v.x + v.y * v.y + v.z * v.z + v.w * v.w;
        union { bf16 h[4]; uint2 u; } pk;
        pk.h[0] = (bf16)v.x; pk.h[1] = (bf16)v.y;
        pk.h[2] = (bf16)v.z; pk.h[3] = (bf16)v.w;
        *((uint2*)(dst + (size_t)(base + l) * ND) + dv) = pk.u;
    }
    for (int o = 32; o; o >>= 1) acc += __shfl_xor(acc, o);
    __shared__ float red[4];
    if ((t & 63) == 0) red[t >> 6] = acc;
    __syncthreads();
    if (t == 0) ss[side * NB + b] = red[0] + red[1] + red[2] + red[3];
}

// ---------------- GEMM: C[b] (128 x NSZ) = A[b](128x512) @ Bop^T ---------
// A row-major [b,m,k]; Bop is N-major x K (attT shared, or B-embed batched).
// EPI==0: store bf16 C (=T). EPI==1: store f32 tanh(acc*scale) to Sout.
template<int NSZ, bool BBATCH, int EPI>
__global__ __launch_bounds__(256) void k_gemm(const bf16* __restrict__ A,
                                              const bf16* __restrict__ Bop,
                                              bf16* __restrict__ Cb,
                                              float* __restrict__ Sout,
                                              const float* __restrict__ ss) {
    const int b  = blockIdx.z;
    const int m0 = blockIdx.y * 64;
    const int n0 = blockIdx.x * 64;
    const int tid = threadIdx.x;

    __shared__ __align__(16) bf16 As[64][40];  // 40: 80B stride, 16B-aligned, 2-way banks (free)
    __shared__ __align__(16) bf16 Bs[64][40];

    const int lane = tid & 63, wv = tid >> 6;
    const int wm = (wv & 1) * 32, wn = (wv >> 1) * 32;
    const int lm = lane & 15, quad = lane >> 4, koff = quad * 8;

    const int rowL = tid >> 2;            // 0..63
    const int kq   = (tid & 3) * 8;       // 0,8,16,24

    const size_t abase = ((size_t)(b * NL + m0 + rowL)) * ND + kq;
    const size_t bbase = (BBATCH ? ((size_t)(b * NL + n0 + rowL)) * ND
                                 : ((size_t)(n0 + rowL)) * ND) + kq;

    f32x4 acc[2][2] = {};

    for (int k0 = 0; k0 < ND; k0 += 32) {
        uint4 va = *(const uint4*)(A   + abase + k0);
        uint4 vb = *(const uint4*)(Bop + bbase + k0);
        *(uint4*)&As[rowL][kq] = va;
        *(uint4*)&Bs[rowL][kq] = vb;
        __syncthreads();
        bf16x8 a0 = *(const bf16x8*)&As[wm + lm     ][koff];
        bf16x8 a1 = *(const bf16x8*)&As[wm + 16 + lm][koff];
        bf16x8 b0 = *(const bf16x8*)&Bs[wn + lm     ][koff];
        bf16x8 b1 = *(const bf16x8*)&Bs[wn + 16 + lm][koff];
        acc[0][0] = __builtin_amdgcn_mfma_f32_16x16x32_bf16(a0, b0, acc[0][0], 0, 0, 0);
        acc[0][1] = __builtin_amdgcn_mfma_f32_16x16x32_bf16(a0, b1, acc[0][1], 0, 0, 0);
        acc[1][0] = __builtin_amdgcn_mfma_f32_16x16x32_bf16(a1, b0, acc[1][0], 0, 0, 0);
        acc[1][1] = __builtin_amdgcn_mfma_f32_16x16x32_bf16(a1, b1, acc[1][1], 0, 0, 0);
        __syncthreads();
    }

    float sc = 1.f;
    if (EPI == 1) sc = rsqrtf(ss[b] * ss[NB + b]);   // 1/(na*nb), linear-deferred norm
    #pragma unroll
    for (int i = 0; i < 2; ++i)
    #pragma unroll
    for (int j = 0; j < 2; ++j)
    #pragma unroll
    for (int p = 0; p < 4; ++p) {
        int m = m0 + wm + i * 16 + quad * 4 + p;   // C/D: col=lane&15, row=quad*4+reg
        int n = n0 + wn + j * 16 + lm;
        if (EPI == 0) {
            Cb[((size_t)b * NL + m) * NSZ + n] = (bf16)acc[i][j][p];
        } else {
            Sout[((size_t)b * NL + m) * NSZ + n] = tanhf(acc[i][j][p] * sc);
        }
    }
}

// ---------------- K3: means -> softmax -> newA/newB -> logits ------------
__global__ __launch_bounds__(256) void k_final(const float* __restrict__ S,
                                               const bf16* __restrict__ Ab,
                                               const bf16* __restrict__ Bb,
                                               const float* __restrict__ ss,
                                               const float* __restrict__ w_pred,
                                               const float* __restrict__ b_pred,
                                               float* __restrict__ logits) {
    const int b = blockIdx.x, t = threadIdx.x;
    const float* __restrict__ Sb = S + (size_t)b * (NL * NL);
    __shared__ float rmean[NL], cmean[NL], wrow[NL], wcol[NL];
    __shared__ float rb[4];

    // col means: threads 0..127, coalesced row sweeps
    if (t < NL) {
        float s = 0.f;
        for (int l = 0; l < NL; ++l) s += Sb[l * NL + t];
        cmean[t] = s * (1.f / NL);
    }
    // row means: wave w handles rows w, w+4, ...
    {
        const int wv = t >> 6, ln = t & 63;
        for (int l = wv; l < NL; l += 4) {
            float s = Sb[l * NL + ln] + Sb[l * NL + ln + 64];
            for (int o = 32; o; o >>= 1) s += __shfl_xor(s, o);
            if (ln == 0) rmean[l] = s * (1.f / NL);
        }
    }
    __syncthreads();

    // softmax over 128: wave0 -> rows, wave1 -> cols
    if (t < 64) {
        float a = rmean[t], c = rmean[t + 64];
        float mx = fmaxf(a, c);
        for (int o = 32; o; o >>= 1) mx = fmaxf(mx, __shfl_xor(mx, o));
        float e0 = expf(a - mx), e1 = expf(c - mx);
        float s = e0 + e1;
        for (int o = 32; o; o >>= 1) s += __shfl_xor(s, o);
        float inv = 1.f / s;
        wrow[t] = e0 * inv; wrow[t + 64] = e1 * inv;
    } else if (t < 128) {
        int q = t - 64;
        float a = cmean[q], c = cmean[q + 64];
        float mx = fmaxf(a, c);
        for (int o = 32; o; o >>= 1) mx = fmaxf(mx, __shfl_xor(mx, o));
        float e0 = expf(a - mx), e1 = expf(c - mx);
        float s = e0 + e1;
        for (int o = 32; o; o >>= 1) s += __shfl_xor(s, o);
        float inv = 1.f / s;
        wcol[q] = e0 * inv; wcol[q + 64] = e1 * inv;
    }
    __syncthreads();

    // newA/newB: thread t owns d = 2t, 2t+1 (bf16 pair = one u32 load)
    const uint32_t* __restrict__ Ar = (const uint32_t*)(Ab + (size_t)b * NL * ND);
    const uint32_t* __restrict__ Br = (const uint32_t*)(Bb + (size_t)b * NL * ND);
    float a0 = 0.f, a1 = 0.f, c0 = 0.f, c1 = 0.f;
    for (int l = 0; l < NL; ++l) {
        float wr = wrow[l], wc = wcol[l];
        uint32_t ua = Ar[l * (ND / 2) + t];
        uint32_t ub = Br[l * (ND / 2) + t];
        a0 += wr * __uint_as_float(ua << 16);
        a1 += wr * __uint_as_float(ua & 0xffff0000u);
        c0 += wc * __uint_as_float(ub << 16);
        c1 += wc * __uint_as_float(ub & 0xffff0000u);
    }
    float invA = rsqrtf(ss[b]), invB = rsqrtf(ss[NB + b]);
    float p = (a0 * invA) * (c0 * invB) * w_pred[2 * t]
            + (a1 * invA) * (c1 * invB) * w_pred[2 * t + 1];
    for (int o = 32; o; o >>= 1) p += __shfl_xor(p, o);
    if ((t & 63) == 0) rb[t >> 6] = p;
    __syncthreads();
    if (t == 0) logits[b] = rb[0] + rb[1] + rb[2] + rb[3] + b_pred[0];
}

extern "C" void kernel_launch(void* const* d_in, const int* in_sizes, int n_in,
                              void* d_out, int out_size, void* d_ws, size_t ws_size,
                              hipStream_t stream) {
    const int*   t1c = (const int*)d_in[2];
    const int*   t2c = (const int*)d_in[3];
    const float* emb = (const float*)d_in[4];
    const float* att = (const float*)d_in[5];
    const float* wp  = (const float*)d_in[6];
    const float* bp  = (const float*)d_in[7];

    float* out    = (float*)d_out;
    float* logits = out;
    float* S      = out + NB;      // outputs: logits(512) then S(512*128*128)

    char* ws = (char*)d_ws;
    bf16*  Ab   = (bf16*)(ws);                              // 67,108,864 B
    bf16*  Bb   = (bf16*)(ws + 67108864);                   // 67,108,864 B
    bf16*  Tb   = (bf16*)(ws + 134217728);                  // 67,108,864 B
    bf16*  attT = (bf16*)(ws + 201326592);                  //    524,288 B
    float* ss   = (float*)(ws + 201850880);                 //      4,096 B

    k_att_t<<<dim3(1024), 256, 0, stream>>>(att, attT);
    k_gather<<<dim3(NB, 2), 256, 0, stream>>>(t1c, t2c, emb, Ab, Bb, ss);
    // T[b] = A[b] @ att   (N=512, B-op = attT, shared)
    k_gemm<512, false, 0><<<dim3(8, 2, NB), 256, 0, stream>>>(Ab, attT, Tb, (float*)nullptr, (const float*)nullptr);
    // S[b] = tanh( (T[b] @ B[b]^T) / (na*nb) )   (N=128, B-op batched)
    k_gemm<128, true, 1><<<dim3(2, 2, NB), 256, 0, stream>>>(Tb, Bb, (bf16*)nullptr, S, ss);
    k_final<<<dim3(NB), 256, 0, stream>>>(S, Ab, Bb, ss, wp, bp, logits);
}

// Round 2
// 436.734 us; speedup vs baseline: 1.2129x; 1.2129x over previous
//
#include <hip/hip_runtime.h>
#include <hip/hip_bf16.h>
#include <stdint.h>

#define NB 512
#define NL 128
#define ND 512

typedef __bf16 bf16;
typedef __bf16 bf16x8 __attribute__((ext_vector_type(8)));
typedef float  f32x4  __attribute__((ext_vector_type(4)));

// ---------------- K0: attT[n*512+k] = bf16(att[k*512+n]) ----------------
__global__ __launch_bounds__(256) void k_att_t(const float* __restrict__ att,
                                               bf16* __restrict__ attT) {
    int i = blockIdx.x * 256 + threadIdx.x;   // over 512*512
    int n = i >> 9, k = i & 511;
    attT[i] = (bf16)att[k * 512 + n];
}

// ---------------- K1: gather embed rows -> bf16, partial sumsq -----------
// grid (NB, 2, 4): block covers 32 rows of one (b, side). 16 independent
// float4 loads per thread -> MLP-bound -> HBM-bound.
__global__ __launch_bounds__(256) void k_gather(const int* __restrict__ ctx1,
                                                const int* __restrict__ ctx2,
                                                const float* __restrict__ table,
                                                bf16* __restrict__ d1,
                                                bf16* __restrict__ d2,
                                                float* __restrict__ ss) {
    const int b = blockIdx.x, side = blockIdx.y, zc = blockIdx.z, t = threadIdx.x;
    const int* __restrict__ ctx = side ? ctx2 : ctx1;
    bf16* __restrict__ dst = side ? d2 : d1;
    const int base = b * NL;
    const int dv = t & 127, lr = t >> 7;
    float acc = 0.f;
    #pragma unroll
    for (int i = 0; i < 16; ++i) {
        int l = zc * 32 + i * 2 + lr;
        int idx = ctx[base + l];
        float4 v = ((const float4*)table)[(size_t)idx * (ND / 4) + dv];
        acc += v.x * v.x + v.y * v.y + v.z * v.z + v.w * v.w;
        union { bf16 h[4]; uint2 u; } pk;
        pk.h[0] = (bf16)v.x; pk.h[1] = (bf16)v.y;
        pk.h[2] = (bf16)v.z; pk.h[3] = (bf16)v.w;
        *((uint2*)(dst + (size_t)(base + l) * ND) + dv) = pk.u;
    }
    for (int o = 32; o; o >>= 1) acc += __shfl_xor(acc, o);
    __shared__ float red[4];
    if ((t & 63) == 0) red[t >> 6] = acc;
    __syncthreads();
    if (t == 0) atomicAdd(&ss[side * NB + b], red[0] + red[1] + red[2] + red[3]);
}

// ---------------- m97-style 128x128 GEMM, BK=64, global_load_lds ---------
// LDS chunk s (16B) holds logical (row r = s>>3, kchunk c = (s&7)^(r&7)).
// XOR swizzle keeps ds_read_b128 fragments at 2-way bank aliasing (free).
// SECOND==false: T[b] = A[b] @ attT^T, store bf16, grid (4, NB).
// SECOND==true:  S[b] = tanh(T[b] @ Bb[b]^T * sc), store f32 + row/col sums,
//                grid (NB).
template<bool SECOND>
__global__ __launch_bounds__(256) void k_gemm(const bf16* __restrict__ A,
                                              const bf16* __restrict__ B,
                                              bf16* __restrict__ Tout,
                                              float* __restrict__ Sout,
                                              const float* __restrict__ ss,
                                              float* __restrict__ rs,
                                              float* __restrict__ cs) {
    const int b     = SECOND ? blockIdx.x : blockIdx.y;
    const int n0    = SECOND ? 0 : blockIdx.x * 128;
    const int arow0 = b * NL;
    const int brow0 = SECOND ? b * NL : n0;
    const int NSZ   = SECOND ? NL : ND;

    __shared__ __align__(16) bf16 As[128 * 64];   // 16 KB
    __shared__ __align__(16) bf16 Bs[128 * 64];   // 16 KB
    __shared__ float rowb[2][128];
    __shared__ float colb[2][128];

    const int tid = threadIdx.x;
    const int lane = tid & 63, w = tid >> 6;
    const int lm = lane & 15, quad = lane >> 4;
    const int wm = (w & 1) * 64, wn = (w >> 1) * 64;

    f32x4 acc[4][4] = {};

    for (int k0 = 0; k0 < ND; k0 += 64) {
        #pragma unroll
        for (int i = 0; i < 4; ++i) {
            int s = w * 256 + i * 64 + lane;
            int r = s >> 3;
            int c = (s & 7) ^ (r & 7);
            const bf16* ga = A + (size_t)(arow0 + r) * ND + k0 + c * 8;
            const bf16* gb = B + (size_t)(brow0 + r) * ND + k0 + c * 8;
            __builtin_amdgcn_global_load_lds(
                (const __attribute__((address_space(1))) void*)ga,
                (__attribute__((address_space(3))) void*)(As + (size_t)(w * 256 + i * 64) * 8),
                16, 0, 0);
            __builtin_amdgcn_global_load_lds(
                (const __attribute__((address_space(1))) void*)gb,
                (__attribute__((address_space(3))) void*)(Bs + (size_t)(w * 256 + i * 64) * 8),
                16, 0, 0);
        }
        __syncthreads();
        #pragma unroll
        for (int kk = 0; kk < 2; ++kk) {
            bf16x8 af[4], bfm[4];
            const int ca = (kk * 4 + quad) ^ (lm & 7);
            #pragma unroll
            for (int t4 = 0; t4 < 4; ++t4) {
                af[t4]  = *(const bf16x8*)&As[(wm + t4 * 16 + lm) * 64 + ca * 8];
                bfm[t4] = *(const bf16x8*)&Bs[(wn + t4 * 16 + lm) * 64 + ca * 8];
            }
            #pragma unroll
            for (int im = 0; im < 4; ++im)
                #pragma unroll
                for (int jn = 0; jn < 4; ++jn)
                    acc[im][jn] = __builtin_amdgcn_mfma_f32_16x16x32_bf16(
                        af[im], bfm[jn], acc[im][jn], 0, 0, 0);
        }
        __syncthreads();
    }

    if (!SECOND) {
        #pragma unroll
        for (int im = 0; im < 4; ++im)
        #pragma unroll
        for (int jn = 0; jn < 4; ++jn)
        #pragma unroll
        for (int p = 0; p < 4; ++p) {
            int m = wm + im * 16 + quad * 4 + p;   // C/D: col=lane&15, row=quad*4+reg
            int n = wn + jn * 16 + lm;
            Tout[(size_t)(arow0 + m) * NSZ + n0 + n] = (bf16)acc[im][jn][p];
        }
    } else {
        const float sc = rsqrtf(ss[b] * ss[NB + b]);   // 1/(na*nb), deferred norm
        float* __restrict__ Sb = Sout + (size_t)b * NL * NL;
        #pragma unroll
        for (int im = 0; im < 4; ++im)
        #pragma unroll
        for (int jn = 0; jn < 4; ++jn)
        #pragma unroll
        for (int p = 0; p < 4; ++p) {
            float v = tanhf(acc[im][jn][p] * sc);
            acc[im][jn][p] = v;
            int m = wm + im * 16 + quad * 4 + p;
            int n = wn + jn * 16 + lm;
            Sb[m * NL + n] = v;
        }
        // row sums (over n): in-lane over jn, shuffle over lm bits (same quad)
        #pragma unroll
        for (int im = 0; im < 4; ++im)
        #pragma unroll
        for (int p = 0; p < 4; ++p) {
            float r = acc[im][0][p] + acc[im][1][p] + acc[im][2][p] + acc[im][3][p];
            r += __shfl_xor(r, 1); r += __shfl_xor(r, 2);
            r += __shfl_xor(r, 4); r += __shfl_xor(r, 8);
            if (lm == 0) rowb[wn >> 6][wm + im * 16 + quad * 4 + p] = r;
        }
        // col sums (over m): in-lane over im,p, shuffle over quad bits
        #pragma unroll
        for (int jn = 0; jn < 4; ++jn) {
            float cv = 0.f;
            #pragma unroll
            for (int im = 0; im < 4; ++im)
                #pragma unroll
                for (int p = 0; p < 4; ++p) cv += acc[im][jn][p];
            cv += __shfl_xor(cv, 16); cv += __shfl_xor(cv, 32);
            if (quad == 0) colb[wm >> 6][wn + jn * 16 + lm] = cv;
        }
        __syncthreads();
        if (tid < 128) rs[b * NL + tid] = rowb[0][tid] + rowb[1][tid];
        else { int u = tid - 128; cs[b * NL + u] = colb[0][u] + colb[1][u]; }
    }
}

// ---------------- K3: softmax(sums) -> newA/newB -> logits ---------------
__global__ __launch_bounds__(256) void k_final(const float* __restrict__ rs,
                                               const float* __restrict__ cs,
                                               const bf16* __restrict__ Ab,
                                               const bf16* __restrict__ Bb,
                                               const float* __restrict__ ss,
                                               const float* __restrict__ w_pred,
                                               const float* __restrict__ b_pred,
                                               float* __restrict__ logits) {
    const int b = blockIdx.x, t = threadIdx.x;
    __shared__ float wrow[NL], wcol[NL];
    __shared__ float pA[4][ND];   // 8 KB
    __shared__ float pB[4][ND];   // 8 KB

    if (t < 64) {
        float a = rs[b * NL + t] * (1.f / NL), c2 = rs[b * NL + t + 64] * (1.f / NL);
        float mx = fmaxf(a, c2);
        for (int o = 32; o; o >>= 1) mx = fmaxf(mx, __shfl_xor(mx, o));
        float e0 = expf(a - mx), e1 = expf(c2 - mx);
        float s = e0 + e1;
        for (int o = 32; o; o >>= 1) s += __shfl_xor(s, o);
        float inv = 1.f / s;
        wrow[t] = e0 * inv; wrow[t + 64] = e1 * inv;
    } else if (t < 128) {
        int q = t - 64;
        float a = cs[b * NL + q] * (1.f / NL), c2 = cs[b * NL + q + 64] * (1.f / NL);
        float mx = fmaxf(a, c2);
        for (int o = 32; o; o >>= 1) mx = fmaxf(mx, __shfl_xor(mx, o));
        float e0 = expf(a - mx), e1 = expf(c2 - mx);
        float s = e0 + e1;
        for (int o = 32; o; o >>= 1) s += __shfl_xor(s, o);
        float inv = 1.f / s;
        wcol[q] = e0 * inv; wcol[q + 64] = e1 * inv;
    }
    __syncthreads();

    // weighted sums: thread (c = t&63, g = t>>6) covers d = c*8..c*8+7,
    // rows l == g (mod 4); 32 independent 16B loads per stream.
    const int c = t & 63, g = t >> 6;
    const bf16* __restrict__ Abase = Ab + (size_t)b * NL * ND;
    const bf16* __restrict__ Bbase = Bb + (size_t)b * NL * ND;
    float aacc[8] = {}, bacc[8] = {};
    for (int l = g; l < NL; l += 4) {
        float wr = wrow[l], wc = wcol[l];
        bf16x8 va = *(const bf16x8*)(Abase + (size_t)l * ND + c * 8);
        bf16x8 vb = *(const bf16x8*)(Bbase + (size_t)l * ND + c * 8);
        #pragma unroll
        for (int j = 0; j < 8; ++j) {
            aacc[j] += wr * (float)va[j];
            bacc[j] += wc * (float)vb[j];
        }
    }
    #pragma unroll
    for (int j = 0; j < 8; ++j) { pA[g][c * 8 + j] = aacc[j]; pB[g][c * 8 + j] = bacc[j]; }
    __syncthreads();

    if (t < 64) {
        float dot = 0.f;
        #pragma unroll
        for (int j = 0; j < 8; ++j) {
            int d = t * 8 + j;
            float na = pA[0][d] + pA[1][d] + pA[2][d] + pA[3][d];
            float nb = pB[0][d] + pB[1][d] + pB[2][d] + pB[3][d];
            dot += na * nb * w_pred[d];
        }
        for (int o = 32; o; o >>= 1) dot += __shfl_xor(dot, o);
        if (t == 0) logits[b] = dot * rsqrtf(ss[b]) * rsqrtf(ss[NB + b]) + b_pred[0];
    }
}

extern "C" void kernel_launch(void* const* d_in, const int* in_sizes, int n_in,
                              void* d_out, int out_size, void* d_ws, size_t ws_size,
                              hipStream_t stream) {
    const int*   t1c = (const int*)d_in[2];
    const int*   t2c = (const int*)d_in[3];
    const float* emb = (const float*)d_in[4];
    const float* att = (const float*)d_in[5];
    const float* wp  = (const float*)d_in[6];
    const float* bp  = (const float*)d_in[7];

    float* out    = (float*)d_out;
    float* logits = out;
    float* S      = out + NB;      // outputs: logits(512) then S(512*128*128)

    char* ws = (char*)d_ws;
    bf16*  Ab   = (bf16*)(ws);                              // 67,108,864 B
    bf16*  Bb   = (bf16*)(ws + 67108864);                   // 67,108,864 B
    bf16*  Tb   = (bf16*)(ws + 134217728);                  // 67,108,864 B
    bf16*  attT = (bf16*)(ws + 201326592);                  //    524,288 B
    float* ss   = (float*)(ws + 201850880);                 //      4,096 B
    float* rs   = (float*)(ws + 201854976);                 //    262,144 B
    float* cs   = (float*)(ws + 202117120);                 //    262,144 B

    hipMemsetAsync(ss, 0, 4096, stream);
    k_att_t<<<dim3(1024), 256, 0, stream>>>(att, attT);
    k_gather<<<dim3(NB, 2, 4), 256, 0, stream>>>(t1c, t2c, emb, Ab, Bb, ss);
    // T = A @ att  (per-batch M=128, N=512, K=512; B-op attT shared)
    k_gemm<false><<<dim3(4, NB), 256, 0, stream>>>(Ab, attT, Tb, (float*)nullptr,
                                                   (const float*)nullptr, nullptr, nullptr);
    // S[b] = tanh(T[b] @ Bb[b]^T * sc) + fused row/col sums
    k_gemm<true><<<dim3(NB), 256, 0, stream>>>(Tb, Bb, (bf16*)nullptr, S, ss, rs, cs);
    k_final<<<dim3(NB), 256, 0, stream>>>(rs, cs, Ab, Bb, ss, wp, bp, logits);
}

// Round 3
// 433.774 us; speedup vs baseline: 1.2211x; 1.0068x over previous
//
#include <hip/hip_runtime.h>
#include <hip/hip_bf16.h>
#include <stdint.h>

#define NB 512
#define NL 128
#define ND 512

typedef __bf16 bf16;
typedef __bf16 bf16x8 __attribute__((ext_vector_type(8)));
typedef float  f32x4  __attribute__((ext_vector_type(4)));

// ---------------- K0: attT[n*512+k] = bf16(att[k*512+n]) ----------------
__global__ __launch_bounds__(256) void k_att_t(const float* __restrict__ att,
                                               bf16* __restrict__ attT) {
    int i = blockIdx.x * 256 + threadIdx.x;   // over 512*512
    int n = i >> 9, k = i & 511;
    attT[i] = (bf16)att[k * 512 + n];
}

// ---------------- K1: gather embed rows -> bf16, partial sumsq -----------
__global__ __launch_bounds__(256) void k_gather(const int* __restrict__ ctx1,
                                                const int* __restrict__ ctx2,
                                                const float* __restrict__ table,
                                                bf16* __restrict__ d1,
                                                bf16* __restrict__ d2,
                                                float* __restrict__ ss) {
    const int b = blockIdx.x, side = blockIdx.y, zc = blockIdx.z, t = threadIdx.x;
    const int* __restrict__ ctx = side ? ctx2 : ctx1;
    bf16* __restrict__ dst = side ? d2 : d1;
    const int base = b * NL;
    const int dv = t & 127, lr = t >> 7;
    float acc = 0.f;
    #pragma unroll
    for (int i = 0; i < 16; ++i) {
        int l = zc * 32 + i * 2 + lr;
        int idx = ctx[base + l];
        float4 v = ((const float4*)table)[(size_t)idx * (ND / 4) + dv];
        acc += v.x * v.x + v.y * v.y + v.z * v.z + v.w * v.w;
        union { bf16 h[4]; uint2 u; } pk;
        pk.h[0] = (bf16)v.x; pk.h[1] = (bf16)v.y;
        pk.h[2] = (bf16)v.z; pk.h[3] = (bf16)v.w;
        *((uint2*)(dst + (size_t)(base + l) * ND) + dv) = pk.u;
    }
    for (int o = 32; o; o >>= 1) acc += __shfl_xor(acc, o);
    __shared__ float red[4];
    if ((t & 63) == 0) red[t >> 6] = acc;
    __syncthreads();
    if (t == 0) atomicAdd(&ss[side * NB + b], red[0] + red[1] + red[2] + red[3]);
}

// ---------------- GEMM1: T = A @ attT^T (m97 structure, 32 KB LDS) -------
// LDS chunk s (16B) holds logical (row r = s>>3, kchunk c = (s&7)^(r&7)).
__global__ __launch_bounds__(256) void k_gemm1(const bf16* __restrict__ A,
                                               const bf16* __restrict__ B,
                                               bf16* __restrict__ Tout) {
    const int b  = blockIdx.y;
    const int n0 = blockIdx.x * 128;
    const int arow0 = b * NL;

    __shared__ __align__(16) bf16 As[128 * 64];   // 16 KB
    __shared__ __align__(16) bf16 Bs[128 * 64];   // 16 KB  (total 32 KB -> 5 blk/CU)

    const int tid = threadIdx.x;
    const int lane = tid & 63, w = tid >> 6;
    const int lm = lane & 15, quad = lane >> 4;
    const int wm = (w & 1) * 64, wn = (w >> 1) * 64;

    f32x4 acc[4][4] = {};

    for (int k0 = 0; k0 < ND; k0 += 64) {
        #pragma unroll
        for (int i = 0; i < 4; ++i) {
            int s = w * 256 + i * 64 + lane;
            int r = s >> 3;
            int c = (s & 7) ^ (r & 7);
            const bf16* ga = A + (size_t)(arow0 + r) * ND + k0 + c * 8;
            const bf16* gb = B + (size_t)(n0 + r) * ND + k0 + c * 8;
            __builtin_amdgcn_global_load_lds(
                (const __attribute__((address_space(1))) void*)ga,
                (__attribute__((address_space(3))) void*)(As + (size_t)(w * 256 + i * 64) * 8),
                16, 0, 0);
            __builtin_amdgcn_global_load_lds(
                (const __attribute__((address_space(1))) void*)gb,
                (__attribute__((address_space(3))) void*)(Bs + (size_t)(w * 256 + i * 64) * 8),
                16, 0, 0);
        }
        __syncthreads();
        #pragma unroll
        for (int kk = 0; kk < 2; ++kk) {
            bf16x8 af[4], bfm[4];
            const int ca = (kk * 4 + quad) ^ (lm & 7);
            #pragma unroll
            for (int t4 = 0; t4 < 4; ++t4) {
                af[t4]  = *(const bf16x8*)&As[(wm + t4 * 16 + lm) * 64 + ca * 8];
                bfm[t4] = *(const bf16x8*)&Bs[(wn + t4 * 16 + lm) * 64 + ca * 8];
            }
            #pragma unroll
            for (int im = 0; im < 4; ++im)
                #pragma unroll
                for (int jn = 0; jn < 4; ++jn)
                    acc[im][jn] = __builtin_amdgcn_mfma_f32_16x16x32_bf16(
                        af[im], bfm[jn], acc[im][jn], 0, 0, 0);
        }
        __syncthreads();
    }

    #pragma unroll
    for (int im = 0; im < 4; ++im)
    #pragma unroll
    for (int jn = 0; jn < 4; ++jn)
    #pragma unroll
    for (int p = 0; p < 4; ++p) {
        int m = wm + im * 16 + quad * 4 + p;   // C/D: col=lane&15, row=quad*4+reg
        int n = wn + jn * 16 + lm;
        Tout[(size_t)(arow0 + m) * ND + n0 + n] = (bf16)acc[im][jn][p];
    }
}

// ---- GEMM2+FINAL: S[b]=tanh(T@Bb^T*sc), sums->softmax->newA/newB->logit --
__global__ __launch_bounds__(256) void k_gemm2_final(
        const bf16* __restrict__ Tin, const bf16* __restrict__ B,
        float* __restrict__ Sout,
        const bf16* __restrict__ Ab, const bf16* __restrict__ Bb,
        const float* __restrict__ ss,
        const float* __restrict__ w_pred, const float* __restrict__ b_pred,
        float* __restrict__ logits) {
    const int b = blockIdx.x;
    const int row0 = b * NL;

    __shared__ __align__(16) char smem[32768];
    bf16* As = (bf16*)smem;              // [128*64], K-loop phase
    bf16* Bs = (bf16*)(smem + 16384);
    float* pA = (float*)smem;            // [4][512], epilogue phase
    float* pB = (float*)(smem + 16384);
    __shared__ float rowb[2][NL], colb[2][NL];
    __shared__ float wrow[NL], wcol[NL];

    const int tid = threadIdx.x;
    const int lane = tid & 63, w = tid >> 6;
    const int lm = lane & 15, quad = lane >> 4;
    const int wm = (w & 1) * 64, wn = (w >> 1) * 64;

    f32x4 acc[4][4] = {};

    for (int k0 = 0; k0 < ND; k0 += 64) {
        #pragma unroll
        for (int i = 0; i < 4; ++i) {
            int s = w * 256 + i * 64 + lane;
            int r = s >> 3;
            int c = (s & 7) ^ (r & 7);
            const bf16* ga = Tin + (size_t)(row0 + r) * ND + k0 + c * 8;
            const bf16* gb = B   + (size_t)(row0 + r) * ND + k0 + c * 8;
            __builtin_amdgcn_global_load_lds(
                (const __attribute__((address_space(1))) void*)ga,
                (__attribute__((address_space(3))) void*)(As + (size_t)(w * 256 + i * 64) * 8),
                16, 0, 0);
            __builtin_amdgcn_global_load_lds(
                (const __attribute__((address_space(1))) void*)gb,
                (__attribute__((address_space(3))) void*)(Bs + (size_t)(w * 256 + i * 64) * 8),
                16, 0, 0);
        }
        __syncthreads();
        #pragma unroll
        for (int kk = 0; kk < 2; ++kk) {
            bf16x8 af[4], bfm[4];
            const int ca = (kk * 4 + quad) ^ (lm & 7);
            #pragma unroll
            for (int t4 = 0; t4 < 4; ++t4) {
                af[t4]  = *(const bf16x8*)&As[(wm + t4 * 16 + lm) * 64 + ca * 8];
                bfm[t4] = *(const bf16x8*)&Bs[(wn + t4 * 16 + lm) * 64 + ca * 8];
            }
            #pragma unroll
            for (int im = 0; im < 4; ++im)
                #pragma unroll
                for (int jn = 0; jn < 4; ++jn)
                    acc[im][jn] = __builtin_amdgcn_mfma_f32_16x16x32_bf16(
                        af[im], bfm[jn], acc[im][jn], 0, 0, 0);
        }
        __syncthreads();
    }

    // ---- epilogue: tanh + S store + row/col sums ----
    const float sc = rsqrtf(ss[b] * ss[NB + b]);   // 1/(na*nb), deferred norm
    float* __restrict__ Sb = Sout + (size_t)b * NL * NL;
    #pragma unroll
    for (int im = 0; im < 4; ++im)
    #pragma unroll
    for (int jn = 0; jn < 4; ++jn)
    #pragma unroll
    for (int p = 0; p < 4; ++p) {
        float v = tanhf(acc[im][jn][p] * sc);
        acc[im][jn][p] = v;
        int m = wm + im * 16 + quad * 4 + p;
        int n = wn + jn * 16 + lm;
        __builtin_nontemporal_store(v, &Sb[m * NL + n]);
    }
    #pragma unroll
    for (int im = 0; im < 4; ++im)
    #pragma unroll
    for (int p = 0; p < 4; ++p) {
        float r = acc[im][0][p] + acc[im][1][p] + acc[im][2][p] + acc[im][3][p];
        r += __shfl_xor(r, 1); r += __shfl_xor(r, 2);
        r += __shfl_xor(r, 4); r += __shfl_xor(r, 8);
        if (lm == 0) rowb[wn >> 6][wm + im * 16 + quad * 4 + p] = r;
    }
    #pragma unroll
    for (int jn = 0; jn < 4; ++jn) {
        float cv = 0.f;
        #pragma unroll
        for (int im = 0; im < 4; ++im)
            #pragma unroll
            for (int p = 0; p < 4; ++p) cv += acc[im][jn][p];
        cv += __shfl_xor(cv, 16); cv += __shfl_xor(cv, 32);
        if (quad == 0) colb[wm >> 6][wn + jn * 16 + lm] = cv;
    }
    __syncthreads();

    // ---- softmax over means (wave0: rows, wave1: cols) ----
    if (tid < 64) {
        float a  = (rowb[0][tid] + rowb[1][tid]) * (1.f / NL);
        float c2 = (rowb[0][tid + 64] + rowb[1][tid + 64]) * (1.f / NL);
        float mx = fmaxf(a, c2);
        for (int o = 32; o; o >>= 1) mx = fmaxf(mx, __shfl_xor(mx, o));
        float e0 = expf(a - mx), e1 = expf(c2 - mx);
        float s = e0 + e1;
        for (int o = 32; o; o >>= 1) s += __shfl_xor(s, o);
        float inv = 1.f / s;
        wrow[tid] = e0 * inv; wrow[tid + 64] = e1 * inv;
    } else if (tid < 128) {
        int q = tid - 64;
        float a  = (colb[0][q] + colb[1][q]) * (1.f / NL);
        float c2 = (colb[0][q + 64] + colb[1][q + 64]) * (1.f / NL);
        float mx = fmaxf(a, c2);
        for (int o = 32; o; o >>= 1) mx = fmaxf(mx, __shfl_xor(mx, o));
        float e0 = expf(a - mx), e1 = expf(c2 - mx);
        float s = e0 + e1;
        for (int o = 32; o; o >>= 1) s += __shfl_xor(s, o);
        float inv = 1.f / s;
        wcol[q] = e0 * inv; wcol[q + 64] = e1 * inv;
    }
    __syncthreads();

    // ---- weighted sums of A/B rows (reuses As/Bs LDS region as pA/pB) ----
    const int c = tid & 63, g = tid >> 6;
    const bf16* __restrict__ Abase = Ab + (size_t)b * NL * ND;
    const bf16* __restrict__ Bbase = Bb + (size_t)b * NL * ND;
    float aacc[8] = {}, bacc[8] = {};
    for (int l = g; l < NL; l += 4) {
        float wr = wrow[l], wc = wcol[l];
        bf16x8 va = *(const bf16x8*)(Abase + (size_t)l * ND + c * 8);
        bf16x8 vb = *(const bf16x8*)(Bbase + (size_t)l * ND + c * 8);
        #pragma unroll
        for (int j = 0; j < 8; ++j) {
            aacc[j] += wr * (float)va[j];
            bacc[j] += wc * (float)vb[j];
        }
    }
    #pragma unroll
    for (int j = 0; j < 8; ++j) {
        pA[g * ND + c * 8 + j] = aacc[j];
        pB[g * ND + c * 8 + j] = bacc[j];
    }
    __syncthreads();

    if (tid < 64) {
        float dot = 0.f;
        #pragma unroll
        for (int j = 0; j < 8; ++j) {
            int d = tid * 8 + j;
            float na = pA[0 * ND + d] + pA[1 * ND + d] + pA[2 * ND + d] + pA[3 * ND + d];
            float nb = pB[0 * ND + d] + pB[1 * ND + d] + pB[2 * ND + d] + pB[3 * ND + d];
            dot += na * nb * w_pred[d];
        }
        for (int o = 32; o; o >>= 1) dot += __shfl_xor(dot, o);
        if (tid == 0)
            logits[b] = dot * rsqrtf(ss[b]) * rsqrtf(ss[NB + b]) + b_pred[0];
    }
}

extern "C" void kernel_launch(void* const* d_in, const int* in_sizes, int n_in,
                              void* d_out, int out_size, void* d_ws, size_t ws_size,
                              hipStream_t stream) {
    const int*   t1c = (const int*)d_in[2];
    const int*   t2c = (const int*)d_in[3];
    const float* emb = (const float*)d_in[4];
    const float* att = (const float*)d_in[5];
    const float* wp  = (const float*)d_in[6];
    const float* bp  = (const float*)d_in[7];

    float* out    = (float*)d_out;
    float* logits = out;
    float* S      = out + NB;      // outputs: logits(512) then S(512*128*128)

    char* ws = (char*)d_ws;
    bf16*  Ab   = (bf16*)(ws);                              // 67,108,864 B
    bf16*  Bb   = (bf16*)(ws + 67108864);                   // 67,108,864 B
    bf16*  Tb   = (bf16*)(ws + 134217728);                  // 67,108,864 B
    bf16*  attT = (bf16*)(ws + 201326592);                  //    524,288 B
    float* ss   = (float*)(ws + 201850880);                 //      4,096 B

    hipMemsetAsync(ss, 0, 4096, stream);
    k_att_t<<<dim3(1024), 256, 0, stream>>>(att, attT);
    k_gather<<<dim3(NB, 2, 4), 256, 0, stream>>>(t1c, t2c, emb, Ab, Bb, ss);
    // T = A @ att  (per-batch M=128, N=512, K=512; B-op attT shared)
    k_gemm1<<<dim3(4, NB), 256, 0, stream>>>(Ab, attT, Tb);
    // S[b] = tanh(T[b] @ Bb[b]^T * sc) + fused sums/softmax/pred
    k_gemm2_final<<<dim3(NB), 256, 0, stream>>>(Tb, Bb, S, Ab, Bb, ss, wp, bp, logits);
}

// Round 4
// 424.043 us; speedup vs baseline: 1.2491x; 1.0229x over previous
//
#include <hip/hip_runtime.h>
#include <hip/hip_bf16.h>
#include <stdint.h>

#define NB 512
#define NL 128
#define ND 512

typedef __bf16 bf16;
typedef __bf16 bf16x8 __attribute__((ext_vector_type(8)));
typedef float  f32x4  __attribute__((ext_vector_type(4)));

// ------- K1: gather embed rows -> bf16 + partial sumsq; y==2: att^T ------
// grid (NB, 3, 8). y<2: block covers 16 rows of (b, side). y==2: blocks with
// chunk = b*8+zc < 1024 transpose+convert att (256 elems each).
__global__ __launch_bounds__(256) void k_gather(const int* __restrict__ ctx1,
                                                const int* __restrict__ ctx2,
                                                const float* __restrict__ table,
                                                bf16* __restrict__ d1,
                                                bf16* __restrict__ d2,
                                                float* __restrict__ ss,
                                                const float* __restrict__ att,
                                                bf16* __restrict__ attT) {
    const int b = blockIdx.x, side = blockIdx.y, zc = blockIdx.z, t = threadIdx.x;
    if (side == 2) {                      // att transpose slice
        int chunk = b * 8 + zc;
        if (chunk < 1024) {
            int i = chunk * 256 + t;      // over 512*512
            int n = i >> 9, k = i & 511;
            attT[i] = (bf16)att[k * 512 + n];
        }
        return;
    }
    const int* __restrict__ ctx = side ? ctx2 : ctx1;
    bf16* __restrict__ dst = side ? d2 : d1;
    const int base = b * NL;
    const int dv = t & 127, lr = t >> 7;
    float acc = 0.f;
    #pragma unroll
    for (int i = 0; i < 8; ++i) {
        int l = zc * 16 + i * 2 + lr;
        int idx = ctx[base + l];
        float4 v = ((const float4*)table)[(size_t)idx * (ND / 4) + dv];
        acc += v.x * v.x + v.y * v.y + v.z * v.z + v.w * v.w;
        union { bf16 h[4]; uint2 u; } pk;
        pk.h[0] = (bf16)v.x; pk.h[1] = (bf16)v.y;
        pk.h[2] = (bf16)v.z; pk.h[3] = (bf16)v.w;
        *((uint2*)(dst + (size_t)(base + l) * ND) + dv) = pk.u;
    }
    for (int o = 32; o; o >>= 1) acc += __shfl_xor(acc, o);
    __shared__ float red[4];
    if ((t & 63) == 0) red[t >> 6] = acc;
    __syncthreads();
    if (t == 0) atomicAdd(&ss[side * NB + b], red[0] + red[1] + red[2] + red[3]);
}

// ---------------- GEMM1: T = A @ attT^T (m97 structure) ------------------
// 1-D grid of 2048 blocks, XCD-co-locating swizzle: the 4 n-chunks of batch
// b share id%8 (same XCD under round-robin) and sit within 32 ids, so A[b]
// (128 KB) is served from that XCD's L2 on 3 of its 4 reads.
__global__ __launch_bounds__(256) void k_gemm1(const bf16* __restrict__ A,
                                               const bf16* __restrict__ B,
                                               bf16* __restrict__ Tout) {
    const int id  = blockIdx.x;
    const int xcd = id & 7;
    const int grp = id >> 3;
    const int n0  = (grp & 3) * 128;
    const int b   = (grp >> 2) * 8 + xcd;
    const int arow0 = b * NL;

    __shared__ __align__(16) bf16 As[128 * 64];   // 16 KB
    __shared__ __align__(16) bf16 Bs[128 * 64];   // 16 KB

    const int tid = threadIdx.x;
    const int lane = tid & 63, w = tid >> 6;
    const int lm = lane & 15, quad = lane >> 4;
    const int wm = (w & 1) * 64, wn = (w >> 1) * 64;

    f32x4 acc[4][4] = {};

    for (int k0 = 0; k0 < ND; k0 += 64) {
        #pragma unroll
        for (int i = 0; i < 4; ++i) {
            int s = w * 256 + i * 64 + lane;
            int r = s >> 3;
            int c = (s & 7) ^ (r & 7);
            const bf16* ga = A + (size_t)(arow0 + r) * ND + k0 + c * 8;
            const bf16* gb = B + (size_t)(n0 + r) * ND + k0 + c * 8;
            __builtin_amdgcn_global_load_lds(
                (const __attribute__((address_space(1))) void*)ga,
                (__attribute__((address_space(3))) void*)(As + (size_t)(w * 256 + i * 64) * 8),
                16, 0, 0);
            __builtin_amdgcn_global_load_lds(
                (const __attribute__((address_space(1))) void*)gb,
                (__attribute__((address_space(3))) void*)(Bs + (size_t)(w * 256 + i * 64) * 8),
                16, 0, 0);
        }
        __syncthreads();
        #pragma unroll
        for (int kk = 0; kk < 2; ++kk) {
            bf16x8 af[4], bfm[4];
            const int ca = (kk * 4 + quad) ^ (lm & 7);
            #pragma unroll
            for (int t4 = 0; t4 < 4; ++t4) {
                af[t4]  = *(const bf16x8*)&As[(wm + t4 * 16 + lm) * 64 + ca * 8];
                bfm[t4] = *(const bf16x8*)&Bs[(wn + t4 * 16 + lm) * 64 + ca * 8];
            }
            #pragma unroll
            for (int im = 0; im < 4; ++im)
                #pragma unroll
                for (int jn = 0; jn < 4; ++jn)
                    acc[im][jn] = __builtin_amdgcn_mfma_f32_16x16x32_bf16(
                        af[im], bfm[jn], acc[im][jn], 0, 0, 0);
        }
        __syncthreads();
    }

    #pragma unroll
    for (int im = 0; im < 4; ++im)
    #pragma unroll
    for (int jn = 0; jn < 4; ++jn)
    #pragma unroll
    for (int p = 0; p < 4; ++p) {
        int m = wm + im * 16 + quad * 4 + p;   // C/D: col=lane&15, row=quad*4+reg
        int n = wn + jn * 16 + lm;
        Tout[(size_t)(arow0 + m) * ND + n0 + n] = (bf16)acc[im][jn][p];
    }
}

// ---- GEMM2+FINAL: S[b]=tanh(T@Bb^T*sc), sums->softmax->newA/newB->logit --
__global__ __launch_bounds__(256) void k_gemm2_final(
        const bf16* __restrict__ Tin, const bf16* __restrict__ B,
        float* __restrict__ Sout,
        const bf16* __restrict__ Ab, const bf16* __restrict__ Bb,
        const float* __restrict__ ss,
        const float* __restrict__ w_pred, const float* __restrict__ b_pred,
        float* __restrict__ logits) {
    const int b = blockIdx.x;
    const int row0 = b * NL;

    __shared__ __align__(16) char smem[32768];
    bf16* As = (bf16*)smem;              // [128*64], K-loop phase
    bf16* Bs = (bf16*)(smem + 16384);
    float* pA = (float*)smem;            // [4][512], epilogue phase
    float* pB = (float*)(smem + 16384);
    __shared__ float rowb[2][NL], colb[2][NL];
    __shared__ float wrow[NL], wcol[NL];

    const int tid = threadIdx.x;
    const int lane = tid & 63, w = tid >> 6;
    const int lm = lane & 15, quad = lane >> 4;
    const int wm = (w & 1) * 64, wn = (w >> 1) * 64;

    f32x4 acc[4][4] = {};

    for (int k0 = 0; k0 < ND; k0 += 64) {
        #pragma unroll
        for (int i = 0; i < 4; ++i) {
            int s = w * 256 + i * 64 + lane;
            int r = s >> 3;
            int c = (s & 7) ^ (r & 7);
            const bf16* ga = Tin + (size_t)(row0 + r) * ND + k0 + c * 8;
            const bf16* gb = B   + (size_t)(row0 + r) * ND + k0 + c * 8;
            __builtin_amdgcn_global_load_lds(
                (const __attribute__((address_space(1))) void*)ga,
                (__attribute__((address_space(3))) void*)(As + (size_t)(w * 256 + i * 64) * 8),
                16, 0, 0);
            __builtin_amdgcn_global_load_lds(
                (const __attribute__((address_space(1))) void*)gb,
                (__attribute__((address_space(3))) void*)(Bs + (size_t)(w * 256 + i * 64) * 8),
                16, 0, 0);
        }
        __syncthreads();
        #pragma unroll
        for (int kk = 0; kk < 2; ++kk) {
            bf16x8 af[4], bfm[4];
            const int ca = (kk * 4 + quad) ^ (lm & 7);
            #pragma unroll
            for (int t4 = 0; t4 < 4; ++t4) {
                af[t4]  = *(const bf16x8*)&As[(wm + t4 * 16 + lm) * 64 + ca * 8];
                bfm[t4] = *(const bf16x8*)&Bs[(wn + t4 * 16 + lm) * 64 + ca * 8];
            }
            #pragma unroll
            for (int im = 0; im < 4; ++im)
                #pragma unroll
                for (int jn = 0; jn < 4; ++jn)
                    acc[im][jn] = __builtin_amdgcn_mfma_f32_16x16x32_bf16(
                        af[im], bfm[jn], acc[im][jn], 0, 0, 0);
        }
        __syncthreads();
    }

    // ---- epilogue: tanh + S store + row/col sums ----
    const float sc = rsqrtf(ss[b] * ss[NB + b]);   // 1/(na*nb), deferred norm
    float* __restrict__ Sb = Sout + (size_t)b * NL * NL;
    #pragma unroll
    for (int im = 0; im < 4; ++im)
    #pragma unroll
    for (int jn = 0; jn < 4; ++jn)
    #pragma unroll
    for (int p = 0; p < 4; ++p) {
        float v = tanhf(acc[im][jn][p] * sc);
        acc[im][jn][p] = v;
        int m = wm + im * 16 + quad * 4 + p;
        int n = wn + jn * 16 + lm;
        __builtin_nontemporal_store(v, &Sb[m * NL + n]);
    }
    #pragma unroll
    for (int im = 0; im < 4; ++im)
    #pragma unroll
    for (int p = 0; p < 4; ++p) {
        float r = acc[im][0][p] + acc[im][1][p] + acc[im][2][p] + acc[im][3][p];
        r += __shfl_xor(r, 1); r += __shfl_xor(r, 2);
        r += __shfl_xor(r, 4); r += __shfl_xor(r, 8);
        if (lm == 0) rowb[wn >> 6][wm + im * 16 + quad * 4 + p] = r;
    }
    #pragma unroll
    for (int jn = 0; jn < 4; ++jn) {
        float cv = 0.f;
        #pragma unroll
        for (int im = 0; im < 4; ++im)
            #pragma unroll
            for (int p = 0; p < 4; ++p) cv += acc[im][jn][p];
        cv += __shfl_xor(cv, 16); cv += __shfl_xor(cv, 32);
        if (quad == 0) colb[wm >> 6][wn + jn * 16 + lm] = cv;
    }
    __syncthreads();

    // ---- softmax over means (wave0: rows, wave1: cols) ----
    if (tid < 64) {
        float a  = (rowb[0][tid] + rowb[1][tid]) * (1.f / NL);
        float c2 = (rowb[0][tid + 64] + rowb[1][tid + 64]) * (1.f / NL);
        float mx = fmaxf(a, c2);
        for (int o = 32; o; o >>= 1) mx = fmaxf(mx, __shfl_xor(mx, o));
        float e0 = expf(a - mx), e1 = expf(c2 - mx);
        float s = e0 + e1;
        for (int o = 32; o; o >>= 1) s += __shfl_xor(s, o);
        float inv = 1.f / s;
        wrow[tid] = e0 * inv; wrow[tid + 64] = e1 * inv;
    } else if (tid < 128) {
        int q = tid - 64;
        float a  = (colb[0][q] + colb[1][q]) * (1.f / NL);
        float c2 = (colb[0][q + 64] + colb[1][q + 64]) * (1.f / NL);
        float mx = fmaxf(a, c2);
        for (int o = 32; o; o >>= 1) mx = fmaxf(mx, __shfl_xor(mx, o));
        float e0 = expf(a - mx), e1 = expf(c2 - mx);
        float s = e0 + e1;
        for (int o = 32; o; o >>= 1) s += __shfl_xor(s, o);
        float inv = 1.f / s;
        wcol[q] = e0 * inv; wcol[q + 64] = e1 * inv;
    }
    __syncthreads();

    // ---- weighted sums of A/B rows (reuses As/Bs LDS region as pA/pB) ----
    const int c = tid & 63, g = tid >> 6;
    const bf16* __restrict__ Abase = Ab + (size_t)b * NL * ND;
    const bf16* __restrict__ Bbase = Bb + (size_t)b * NL * ND;
    float aacc[8] = {}, bacc[8] = {};
    for (int l = g; l < NL; l += 4) {
        float wr = wrow[l], wc = wcol[l];
        bf16x8 va = *(const bf16x8*)(Abase + (size_t)l * ND + c * 8);
        bf16x8 vb = *(const bf16x8*)(Bbase + (size_t)l * ND + c * 8);
        #pragma unroll
        for (int j = 0; j < 8; ++j) {
            aacc[j] += wr * (float)va[j];
            bacc[j] += wc * (float)vb[j];
        }
    }
    #pragma unroll
    for (int j = 0; j < 8; ++j) {
        pA[g * ND + c * 8 + j] = aacc[j];
        pB[g * ND + c * 8 + j] = bacc[j];
    }
    __syncthreads();

    if (tid < 64) {
        float dot = 0.f;
        #pragma unroll
        for (int j = 0; j < 8; ++j) {
            int d = tid * 8 + j;
            float na = pA[0 * ND + d] + pA[1 * ND + d] + pA[2 * ND + d] + pA[3 * ND + d];
            float nb = pB[0 * ND + d] + pB[1 * ND + d] + pB[2 * ND + d] + pB[3 * ND + d];
            dot += na * nb * w_pred[d];
        }
        for (int o = 32; o; o >>= 1) dot += __shfl_xor(dot, o);
        if (tid == 0)
            logits[b] = dot * rsqrtf(ss[b]) * rsqrtf(ss[NB + b]) + b_pred[0];
    }
}

extern "C" void kernel_launch(void* const* d_in, const int* in_sizes, int n_in,
                              void* d_out, int out_size, void* d_ws, size_t ws_size,
                              hipStream_t stream) {
    const int*   t1c = (const int*)d_in[2];
    const int*   t2c = (const int*)d_in[3];
    const float* emb = (const float*)d_in[4];
    const float* att = (const float*)d_in[5];
    const float* wp  = (const float*)d_in[6];
    const float* bp  = (const float*)d_in[7];

    float* out    = (float*)d_out;
    float* logits = out;
    float* S      = out + NB;      // outputs: logits(512) then S(512*128*128)

    char* ws = (char*)d_ws;
    bf16*  Ab   = (bf16*)(ws);                              // 67,108,864 B
    bf16*  Bb   = (bf16*)(ws + 67108864);                   // 67,108,864 B
    bf16*  Tb   = (bf16*)(ws + 134217728);                  // 67,108,864 B
    bf16*  attT = (bf16*)(ws + 201326592);                  //    524,288 B
    float* ss   = (float*)(ws + 201850880);                 //      4,096 B

    hipMemsetAsync(ss, 0, 4096, stream);
    // gather (y=0,1) + att transpose (y=2) in one launch
    k_gather<<<dim3(NB, 3, 8), 256, 0, stream>>>(t1c, t2c, emb, Ab, Bb, ss, att, attT);
    // T = A @ att; 1-D grid with XCD-co-locating swizzle
    k_gemm1<<<dim3(2048), 256, 0, stream>>>(Ab, attT, Tb);
    // S[b] = tanh(T[b] @ Bb[b]^T * sc) + fused sums/softmax/pred
    k_gemm2_final<<<dim3(NB), 256, 0, stream>>>(Tb, Bb, S, Ab, Bb, ss, wp, bp, logits);
}